// Round 10
// baseline (276.066 us; speedup 1.0000x reference)
//
#include <hip/hip_runtime.h>

#define N_ 8
#define C_ 48
#define H_ 48
#define W_ 64
#define HO 384
#define WO 512
#define HW (H_*W_)   // 3072

typedef float f32x4 __attribute__((ext_vector_type(4)));

// DIAGNOSTIC ROUND: exact R6 kernel body executed 3x in one dispatch (opaque
// pointer perturbation defeats CSE), so the dispatch exceeds the harness fill
// ops (~175us) and finally shows up in the rocprof top-5 with FETCH/WRITE.
// Output values identical each pass -> still correct & deterministic.
__global__ __launch_bounds__(256, 3) void raft_up_kernel(
    const float* __restrict__ inp, const float* __restrict__ mask,
    float* __restrict__ out)
{
    const int t   = threadIdx.x;
    const int bid = blockIdx.x;            // (n*H + h)*4 + pg
    const int pg  = bid & 3;
    const int h   = (bid >> 2) % H_;
    const int n   = bid / (4 * H_);

    const int tq    = t & 127;
    const int chalf = t >> 7;              // 0: c 0..23, 1: c 24..47
    const int q4    = tq & 1;              // q quad (q = q4*4 + j)
    const int wi    = tq >> 1;             // 0..63 (w coordinate)

    const bool rok0 = (h >= 1), rok2 = (h <= H_ - 2);
    const bool cok0 = (wi >= 1), cok2 = (wi <= W_ - 2);
    const bool ok[3][3] = {
        { rok0 && cok0, rok0, rok0 && cok2 },
        { cok0,         true, cok2         },
        { rok2 && cok0, rok2, rok2 && cok2 },
    };

    for (int pass = 0; pass < 3; ++pass) {
        // opaque copies: compiler cannot prove passes identical -> no hoisting
        const float* mk = mask;
        const float* ip = inp;
        float*       op = out;
        asm volatile("" : "+v"(mk), "+v"(ip), "+v"(op));

        // ---- softmax over 9 taps for my 8 planes (pl x 4 q's)
        f32x4 w[2][9];
        {
            const float* mb = mk + ((size_t)n * 576 + pg * 16 + q4 * 4) * HW
                                 + h * W_ + wi;
            #pragma unroll
            for (int pl = 0; pl < 2; ++pl)
                #pragma unroll
                for (int k = 0; k < 9; ++k)
                    #pragma unroll
                    for (int j = 0; j < 4; ++j)
                        w[pl][k][j] = mb[(size_t)(k * 64 + pl * 8 + j) * HW];

            #pragma unroll
            for (int pl = 0; pl < 2; ++pl) {
                f32x4 mx = w[pl][0];
                #pragma unroll
                for (int k = 1; k < 9; ++k) {
                    mx.x = fmaxf(mx.x, w[pl][k].x); mx.y = fmaxf(mx.y, w[pl][k].y);
                    mx.z = fmaxf(mx.z, w[pl][k].z); mx.w = fmaxf(mx.w, w[pl][k].w);
                }
                f32x4 s = (f32x4){0.f, 0.f, 0.f, 0.f};
                #pragma unroll
                for (int k = 0; k < 9; ++k) {
                    f32x4 e;
                    e.x = __expf(w[pl][k].x - mx.x);
                    e.y = __expf(w[pl][k].y - mx.y);
                    e.z = __expf(w[pl][k].z - mx.z);
                    e.w = __expf(w[pl][k].w - mx.w);
                    w[pl][k] = e;
                    s += e;
                }
                f32x4 inv;
                inv.x = 1.f / s.x; inv.y = 1.f / s.y;
                inv.z = 1.f / s.z; inv.w = 1.f / s.w;
                #pragma unroll
                for (int k = 0; k < 9; ++k) w[pl][k] *= inv;
            }
        }

        const float* ib = ip + (size_t)(n * C_ + chalf * 24) * HW + (wi - 1);
        float* outb = op + ((size_t)(n * C_ + chalf * 24) * HO + h * 8 + pg * 2) * WO
                         + wi * 8 + q4 * 4;

        for (int cblk = 0; cblk < 6; ++cblk) {
            float tp[4][9];
            #pragma unroll
            for (int di = 0; di < 3; ++di)
                #pragma unroll
                for (int dj = 0; dj < 3; ++dj) {
                    const bool o = ok[di][dj];
                    #pragma unroll
                    for (int cc = 0; cc < 4; ++cc) {
                        const float* p = ib + (size_t)((cblk * 4 + cc) * H_ + h - 1 + di) * W_ + dj;
                        tp[cc][di * 3 + dj] = o ? *p : 0.f;
                    }
                }
            #pragma unroll
            for (int cc = 0; cc < 4; ++cc)
                #pragma unroll
                for (int pl = 0; pl < 2; ++pl) {
                    f32x4 acc = w[pl][0] * tp[cc][0];
                    #pragma unroll
                    for (int k = 1; k < 9; ++k)
                        acc += w[pl][k] * tp[cc][k];
                    *(f32x4*)(outb + ((size_t)(cblk * 4 + cc) * HO + pl) * WO) = acc;
                }
        }
    }
}

extern "C" void kernel_launch(void* const* d_in, const int* in_sizes, int n_in,
                              void* d_out, int out_size, void* d_ws, size_t ws_size,
                              hipStream_t stream) {
    const float* inp  = (const float*)d_in[0];
    const float* mask = (const float*)d_in[1];
    float* out = (float*)d_out;
    const int blocks = N_ * H_ * 4;   // 8*48*4 = 1536
    raft_up_kernel<<<blocks, 256, 0, stream>>>(inp, mask, out);
}

// Round 11
// 98.485 us; speedup vs baseline: 2.8031x; 2.8031x over previous
//
#include <hip/hip_runtime.h>

#define N_ 8
#define C_ 48
#define H_ 48
#define W_ 64
#define HO 384
#define WO 512
#define HW (H_*W_)   // 3072

typedef float f32x4 __attribute__((ext_vector_type(4)));

// out[n][c][h*8+p][w*8+q] = sum_k softmax_k(mask[n][k*64+p*8+q][h][w]) * inp_pad[n][c][h+di-1][w+dj-1]
// R6 zero-LDS design with p split 8-way (was 4-way pg):
//   3072 blocks (12/CU -> refill queue), per-thread chains halved
//   (36 mask loads, w[9]=36 VGPR, 24 short independent channel iterations).
__global__ __launch_bounds__(256, 6) void raft_up_kernel(
    const float* __restrict__ inp, const float* __restrict__ mask,
    float* __restrict__ out)
{
    const int t   = threadIdx.x;
    const int bid = blockIdx.x;            // (n*H + h)*8 + p
    const int p   = bid & 7;
    const int h   = (bid >> 3) % H_;
    const int n   = bid / (8 * H_);

    const int tq    = t & 127;
    const int chalf = t >> 7;              // 0: c 0..23, 1: c 24..47
    const int q4    = tq & 1;              // q quad (q = q4*4 + j)
    const int wi    = tq >> 1;             // 0..63 (w coordinate)

    // ---- softmax over 9 taps for my plane p, 4 q's (f32x4 lanes = j)
    // mask channel = k*64 + p*8 + q4*4 + j
    f32x4 w[9];
    {
        const float* mb = mask + ((size_t)n * 576 + p * 8 + q4 * 4) * HW
                               + h * W_ + wi;
        #pragma unroll
        for (int k = 0; k < 9; ++k)
            #pragma unroll
            for (int j = 0; j < 4; ++j)
                w[k][j] = mb[(size_t)(k * 64 + j) * HW];

        f32x4 mx = w[0];
        #pragma unroll
        for (int k = 1; k < 9; ++k) {
            mx.x = fmaxf(mx.x, w[k].x); mx.y = fmaxf(mx.y, w[k].y);
            mx.z = fmaxf(mx.z, w[k].z); mx.w = fmaxf(mx.w, w[k].w);
        }
        f32x4 s = (f32x4){0.f, 0.f, 0.f, 0.f};
        #pragma unroll
        for (int k = 0; k < 9; ++k) {
            f32x4 e;
            e.x = __expf(w[k].x - mx.x);
            e.y = __expf(w[k].y - mx.y);
            e.z = __expf(w[k].z - mx.z);
            e.w = __expf(w[k].w - mx.w);
            w[k] = e;
            s += e;
        }
        f32x4 inv;
        inv.x = 1.f / s.x; inv.y = 1.f / s.y;
        inv.z = 1.f / s.z; inv.w = 1.f / s.w;
        #pragma unroll
        for (int k = 0; k < 9; ++k) w[k] *= inv;
    }

    // ---- tap validity (zero padding)
    const bool rok0 = (h >= 1), rok2 = (h <= H_ - 2);
    const bool cok0 = (wi >= 1), cok2 = (wi <= W_ - 2);
    const bool ok[3][3] = {
        { rok0 && cok0, rok0, rok0 && cok2 },
        { cok0,         true, cok2         },
        { rok2 && cok0, rok2, rok2 && cok2 },
    };

    const float* ib = inp + (size_t)(n * C_ + chalf * 24) * HW + (wi - 1);
    float* outb = out + ((size_t)(n * C_ + chalf * 24) * HO + h * 8 + p) * WO
                      + wi * 8 + q4 * 4;

    // 24 short, independent channel iterations: 9 loads -> 9 FMA -> 1 store
    #pragma unroll 2
    for (int cp = 0; cp < 24; ++cp) {
        float tp[9];
        #pragma unroll
        for (int di = 0; di < 3; ++di)
            #pragma unroll
            for (int dj = 0; dj < 3; ++dj) {
                const float* ap = ib + (size_t)(cp * H_ + h - 1 + di) * W_ + dj;
                tp[di * 3 + dj] = ok[di][dj] ? *ap : 0.f;
            }
        f32x4 acc = w[0] * tp[0];
        #pragma unroll
        for (int k = 1; k < 9; ++k)
            acc += w[k] * tp[k];
        *(f32x4*)(outb + (size_t)cp * HO * WO) = acc;
    }
}

extern "C" void kernel_launch(void* const* d_in, const int* in_sizes, int n_in,
                              void* d_out, int out_size, void* d_ws, size_t ws_size,
                              hipStream_t stream) {
    const float* inp  = (const float*)d_in[0];
    const float* mask = (const float*)d_in[1];
    float* out = (float*)d_out;
    const int blocks = N_ * H_ * 8;   // 8*48*8 = 3072
    raft_up_kernel<<<blocks, 256, 0, stream>>>(inp, mask, out);
}

// Round 12
// 84.204 us; speedup vs baseline: 3.2785x; 1.1696x over previous
//
#include <hip/hip_runtime.h>

#define N_ 8
#define C_ 48
#define H_ 48
#define W_ 64
#define HO 384
#define WO 512
#define HW (H_*W_)   // 3072

typedef float f32x4 __attribute__((ext_vector_type(4)));

// out[n][c][h*8+p][w*8+q] = sum_k softmax_k(mask[n][k*64+p*8+q][h][w]) * inp_pad[n][c][h+di-1][w+dj-1]
// R6 zero-LDS design + nontemporal hints (single-variable A/B vs R6):
//   - nt stores on the 302MB output stream (never re-read; keep out of L2)
//   - nt loads on the 57MB read-once mask stream
// Tap loads stay cached (heavy L2 reuse). Everything else identical to R6 (90.9us).
__global__ __launch_bounds__(256, 3) void raft_up_kernel(
    const float* __restrict__ inp, const float* __restrict__ mask,
    float* __restrict__ out)
{
    const int t   = threadIdx.x;
    const int bid = blockIdx.x;            // (n*H + h)*4 + pg
    const int pg  = bid & 3;
    const int h   = (bid >> 2) % H_;
    const int n   = bid / (4 * H_);

    const int tq    = t & 127;
    const int chalf = t >> 7;              // 0: c 0..23, 1: c 24..47
    const int q4    = tq & 1;              // q quad (q = q4*4 + j)
    const int wi    = tq >> 1;             // 0..63 (w coordinate)

    // ---- softmax over 9 taps for my 8 planes (pl x 4 q's); f32x4 lanes = j (q)
    f32x4 w[2][9];
    {
        const float* mb = mask + ((size_t)n * 576 + pg * 16 + q4 * 4) * HW
                               + h * W_ + wi;
        #pragma unroll
        for (int pl = 0; pl < 2; ++pl)
            #pragma unroll
            for (int k = 0; k < 9; ++k)
                #pragma unroll
                for (int j = 0; j < 4; ++j)
                    w[pl][k][j] = __builtin_nontemporal_load(
                        mb + (size_t)(k * 64 + pl * 8 + j) * HW);

        #pragma unroll
        for (int pl = 0; pl < 2; ++pl) {
            f32x4 mx = w[pl][0];
            #pragma unroll
            for (int k = 1; k < 9; ++k) {
                mx.x = fmaxf(mx.x, w[pl][k].x); mx.y = fmaxf(mx.y, w[pl][k].y);
                mx.z = fmaxf(mx.z, w[pl][k].z); mx.w = fmaxf(mx.w, w[pl][k].w);
            }
            f32x4 s = (f32x4){0.f, 0.f, 0.f, 0.f};
            #pragma unroll
            for (int k = 0; k < 9; ++k) {
                f32x4 e;
                e.x = __expf(w[pl][k].x - mx.x);
                e.y = __expf(w[pl][k].y - mx.y);
                e.z = __expf(w[pl][k].z - mx.z);
                e.w = __expf(w[pl][k].w - mx.w);
                w[pl][k] = e;
                s += e;
            }
            f32x4 inv;
            inv.x = 1.f / s.x; inv.y = 1.f / s.y;
            inv.z = 1.f / s.z; inv.w = 1.f / s.w;
            #pragma unroll
            for (int k = 0; k < 9; ++k) w[pl][k] *= inv;
        }
    }

    // ---- tap validity (zero padding)
    const bool rok0 = (h >= 1), rok2 = (h <= H_ - 2);
    const bool cok0 = (wi >= 1), cok2 = (wi <= W_ - 2);
    const bool ok[3][3] = {
        { rok0 && cok0, rok0, rok0 && cok2 },
        { cok0,         true, cok2         },
        { rok2 && cok0, rok2, rok2 && cok2 },
    };

    const float* ib = inp + (size_t)(n * C_ + chalf * 24) * HW + (wi - 1);
    float* outb = out + ((size_t)(n * C_ + chalf * 24) * HO + h * 8 + pg * 2) * WO
                      + wi * 8 + q4 * 4;

    for (int cblk = 0; cblk < 6; ++cblk) {
        // taps for 4 channels, read from L2-resident inp (cached loads)
        float tp[4][9];
        #pragma unroll
        for (int di = 0; di < 3; ++di)
            #pragma unroll
            for (int dj = 0; dj < 3; ++dj) {
                const bool o = ok[di][dj];
                #pragma unroll
                for (int cc = 0; cc < 4; ++cc) {
                    const float* p = ib + (size_t)((cblk * 4 + cc) * H_ + h - 1 + di) * W_ + dj;
                    tp[cc][di * 3 + dj] = o ? *p : 0.f;
                }
            }
        #pragma unroll
        for (int cc = 0; cc < 4; ++cc)
            #pragma unroll
            for (int pl = 0; pl < 2; ++pl) {
                f32x4 acc = w[pl][0] * tp[cc][0];
                #pragma unroll
                for (int k = 1; k < 9; ++k)
                    acc += w[pl][k] * tp[cc][k];
                __builtin_nontemporal_store(acc,
                    (f32x4*)(outb + ((size_t)(cblk * 4 + cc) * HO + pl) * WO));
            }
    }
}

extern "C" void kernel_launch(void* const* d_in, const int* in_sizes, int n_in,
                              void* d_out, int out_size, void* d_ws, size_t ws_size,
                              hipStream_t stream) {
    const float* inp  = (const float*)d_in[0];
    const float* mask = (const float*)d_in[1];
    float* out = (float*)d_out;
    const int blocks = N_ * H_ * 4;   // 8*48*4 = 1536
    raft_up_kernel<<<blocks, 256, 0, stream>>>(inp, mask, out);
}